// Round 1
// baseline (47.359 us; speedup 1.0000x reference)
//
#include <hip/hip_runtime.h>

// Problem constants (from reference setup_inputs):
//   imgs: (B=8, C=128, H=512, W=512) float32  (1 GiB)
//   batch_points: (B=8, P=2048, 2) int64, values in [0,512)
//   out: (B*P, C) float32 = (16384, 128)  + scalar length=16384 appended
#define NB 8
#define NC 128
#define NH 512
#define NW 512
#define NP 2048

__global__ __launch_bounds__(256) void crop_gather_kernel(
    const float* __restrict__ imgs,
    const long long* __restrict__ pts,   // (B*P, 2) int64: [x, y]
    float* __restrict__ out)
{
    // One thread handles 4 consecutive channels of one output row.
    // 32 threads per row -> float4 coalesced output stores.
    int tid = blockIdx.x * 256 + threadIdx.x;        // 0 .. B*P*C/4-1
    int row = tid >> 5;                              // b*P + p  (0..16383)
    int t   = tid & 31;
    int c0  = t << 2;                                // channel base 0..124

    long long xl = pts[(size_t)row * 2 + 0];         // x
    long long yl = pts[(size_t)row * 2 + 1];         // y
    int x = (int)xl;
    int y = (int)yl;
    int b = row >> 11;                               // row / P

    const size_t plane = (size_t)NH * NW;            // 262144
    const float* src = imgs + ((size_t)(b * NC + c0)) * plane
                            + (size_t)y * NW + (size_t)x;

    // 4 independent 1MiB-strided loads in flight per thread.
    float4 v;
    v.x = src[0];
    v.y = src[plane];
    v.z = src[2 * plane];
    v.w = src[3 * plane];

    *reinterpret_cast<float4*>(out + (size_t)row * NC + c0) = v;

    // Second tuple element: length = B*P = 16384, stored as float after out.
    if (tid == 0) {
        out[(size_t)NB * NP * NC] = 16384.0f;
    }
}

extern "C" void kernel_launch(void* const* d_in, const int* in_sizes, int n_in,
                              void* d_out, int out_size, void* d_ws, size_t ws_size,
                              hipStream_t stream) {
    const float* imgs = (const float*)d_in[0];
    const long long* pts = (const long long*)d_in[1];
    float* out = (float*)d_out;

    const int total_threads = NB * NP * NC / 4;      // 524288
    const int block = 256;
    const int grid = total_threads / block;          // 2048

    crop_gather_kernel<<<grid, block, 0, stream>>>(imgs, pts, out);
}

// Round 2
// 46.713 us; speedup vs baseline: 1.0138x; 1.0138x over previous
//
#include <hip/hip_runtime.h>

// Problem constants (from reference setup_inputs):
//   imgs: (B=8, C=128, H=512, W=512) float32  (1 GiB)
//   batch_points: (B=8, P=2048, 2) — declared int64 but JAX x64 is disabled,
//                 so the actual array is INT32 (harness: integer -> const int*).
//   out: (B*P, C) float32 = (16384, 128)  + scalar length=16384 appended
#define NB 8
#define NC 128
#define NH 512
#define NW 512
#define NP 2048

__global__ __launch_bounds__(256) void crop_gather_kernel(
    const float* __restrict__ imgs,
    const int* __restrict__ pts,         // (B*P, 2) int32: [x, y]
    float* __restrict__ out)
{
    // One thread handles 4 consecutive channels of one output row.
    // 32 threads per row -> float4 coalesced output stores.
    int tid = blockIdx.x * 256 + threadIdx.x;        // 0 .. B*P*C/4-1
    int row = tid >> 5;                              // b*P + p  (0..16383)
    int t   = tid & 31;
    int c0  = t << 2;                                // channel base 0..124

    int x = pts[row * 2 + 0];                        // W index
    int y = pts[row * 2 + 1];                        // H index
    int b = row >> 11;                               // row / P

    const size_t plane = (size_t)NH * NW;            // 262144
    const float* src = imgs + ((size_t)(b * NC + c0)) * plane
                            + (size_t)y * NW + (size_t)x;

    // 4 independent 1MiB-strided loads in flight per thread.
    float4 v;
    v.x = src[0];
    v.y = src[plane];
    v.z = src[2 * plane];
    v.w = src[3 * plane];

    *reinterpret_cast<float4*>(out + (size_t)row * NC + c0) = v;

    // Second tuple element: length = B*P = 16384, stored as float after out.
    if (tid == 0) {
        out[(size_t)NB * NP * NC] = 16384.0f;
    }
}

extern "C" void kernel_launch(void* const* d_in, const int* in_sizes, int n_in,
                              void* d_out, int out_size, void* d_ws, size_t ws_size,
                              hipStream_t stream) {
    const float* imgs = (const float*)d_in[0];
    const int* pts = (const int*)d_in[1];
    float* out = (float*)d_out;

    const int total_threads = NB * NP * NC / 4;      // 524288
    const int block = 256;
    const int grid = total_threads / block;          // 2048

    crop_gather_kernel<<<grid, block, 0, stream>>>(imgs, pts, out);
}